// Round 6
// baseline (3356.719 us; speedup 1.0000x reference)
//
#include <hip/hip_runtime.h>

#define LATENT 32
#define NN     100000
#define E1N    3200000
#define N2N    200000
#define E2N    3200000
#define MN     131072
#define EPSV   1e-5f

#define BK_SH     7          // 128 nodes per bucket
#define PACK_SH   20         // src in bits 0..19, dst_local in bits 20..26
#define PACK_MASK 0xFFFFF
#define NBKT1     782        // ceil(100000/128)
#define NBKT2     1563       // ceil(200000/128)

// ---------------- workspace layout (bytes) ----------------
// hA [25.6MB]  : pair h ping buffer; temp bucketed-edge storage during CSR build
// hB [25.6MB]  : pair h pong buffer; csr1 lives in its 2nd half until k_pair
constexpr size_t OFF_HA    = 0;
constexpr size_t OFF_HB    = 25600000;
constexpr size_t OFF_CSR1  = OFF_HB + 12800000;        // overlays hB 2nd half (dead before k_pair)
constexpr size_t OFF_CSR2  = 51200000;
constexpr size_t OFF_CSR2R = 64000000;
constexpr size_t OFF_OFF1  = 76800000;                 // (NN+1)*4
constexpr size_t OFF_OFF2  = OFF_OFF1 + 400128;        // (N2N+1)*4
constexpr size_t OFF_OFF2R = OFF_OFF2 + 800128;
constexpr size_t OFF_BC    = OFF_OFF2R + 800128;       // 9 arrays x 2048 ints
constexpr size_t OFF_STATS = OFF_BC + 73728;
constexpr size_t OFF_AFF   = OFF_STATS + 256;          // total ~78.9 MB

// ---------------- embedding + GraphNorm ----------------

__global__ void k_embed_stats(const int* __restrict__ x, const float* __restrict__ emb,
                              float* __restrict__ h, float* __restrict__ stats, int n) {
    __shared__ float lsum[256], lsq[256];
    int tid = threadIdx.x;
    float s = 0.f, q = 0.f;
    int stride = gridDim.x * blockDim.x;
    for (int idx = blockIdx.x * blockDim.x + tid; idx < n * 32; idx += stride) {
        int i = idx >> 5, k = idx & 31;
        float v = emb[x[i] * 32 + k];
        h[idx] = v;
        s += v; q += v * v;
    }
    lsum[tid] = s; lsq[tid] = q;
    __syncthreads();
    if (tid < 32) {
        float ts = 0.f, tq = 0.f;
        #pragma unroll
        for (int r = 0; r < 8; ++r) { ts += lsum[tid + r * 32]; tq += lsq[tid + r * 32]; }
        atomicAdd(&stats[tid], ts);
        atomicAdd(&stats[32 + tid], tq);
    }
}

__global__ void k_affine(const float* __restrict__ stats, const float* __restrict__ w,
                         const float* __restrict__ b, const float* __restrict__ ms,
                         float* __restrict__ aff, int n) {
    int k = threadIdx.x;
    if (k < 32) {
        float mean = stats[k] / (float)n;
        float m2   = stats[32 + k] / (float)n;
        float m    = ms[k];
        float var  = m2 - 2.f * m * mean * mean + m * m * mean * mean;
        float A    = w[k] / sqrtf(var + EPSV);
        aff[k]      = A;
        aff[32 + k] = b[k] - A * m * mean;
    }
}

__global__ void k_apply_affine(float* __restrict__ h, const float* __restrict__ aff, int total) {
    int idx = blockIdx.x * blockDim.x + threadIdx.x;
    int stride = gridDim.x * blockDim.x;
    for (; idx < total; idx += stride) {
        int k = idx & 31;
        h[idx] = h[idx] * aff[k] + aff[32 + k];
    }
}

// ---------------- bucketed CSR build ----------------

__global__ void k_bcount2(const int* __restrict__ dF, int* __restrict__ cF,
                          const int* __restrict__ dR, int* __restrict__ cR, int ne) {
    int idx = blockIdx.x * blockDim.x + threadIdx.x;
    int stride = gridDim.x * blockDim.x;
    for (; idx < ne; idx += stride) {
        atomicAdd(&cF[dF[idx] >> BK_SH], 1);
        atomicAdd(&cR[dR[idx] >> BK_SH], 1);
    }
}

__global__ void k_bcount(const int* __restrict__ d, int* __restrict__ c, int ne) {
    int idx = blockIdx.x * blockDim.x + threadIdx.x;
    int stride = gridDim.x * blockDim.x;
    for (; idx < ne; idx += stride) atomicAdd(&c[d[idx] >> BK_SH], 1);
}

// exclusive scan of three bucket-count arrays (each <= 1564 entries)
__global__ void k_bscan3(int* cF, int* bF, int* uF, int nF,
                         int* cR, int* bR, int* uR, int nR,
                         int* c1, int* b1, int* u1, int n1) {
    int* c; int* bs; int* u; int n;
    if (blockIdx.x == 0)      { c = cF; bs = bF; u = uF; n = nF; }
    else if (blockIdx.x == 1) { c = cR; bs = bR; u = uR; n = nR; }
    else                      { c = c1; bs = b1; u = u1; n = n1; }
    __shared__ int lds[256];
    int t = threadIdx.x;
    int v[7]; int run = 0;
    #pragma unroll
    for (int j = 0; j < 7; ++j) {
        int e = t * 7 + j;
        v[j] = (e < n) ? c[e] : 0;
        run += v[j];
    }
    int tot = run;
    lds[t] = tot; __syncthreads();
    for (int o = 1; o < 256; o <<= 1) {
        int add = (t >= o) ? lds[t - o] : 0;
        __syncthreads();
        lds[t] += add;
        __syncthreads();
    }
    int run2 = lds[t] - tot;
    #pragma unroll
    for (int j = 0; j < 7; ++j) {
        int e = t * 7 + j;
        if (e <= n) {
            bs[e] = run2;
            if (e < n) u[e] = run2;
            run2 += v[j];
        }
    }
}

// scatter edges into bucket-sorted temp array (packed src|dst_local)
__global__ void k_bfill2(const int* __restrict__ sF, const int* __restrict__ dF,
                         int* __restrict__ uF, int* __restrict__ beF,
                         const int* __restrict__ sR, const int* __restrict__ dR,
                         int* __restrict__ uR, int* __restrict__ beR, int ne) {
    int idx = blockIdx.x * blockDim.x + threadIdx.x;
    int stride = gridDim.x * blockDim.x;
    for (; idx < ne; idx += stride) {
        int d0 = dF[idx], d1 = dR[idx];
        int p0 = atomicAdd(&uF[d0 >> BK_SH], 1);
        int p1 = atomicAdd(&uR[d1 >> BK_SH], 1);
        beF[p0] = sF[idx] | ((d0 & 127) << PACK_SH);
        beR[p1] = sR[idx] | ((d1 & 127) << PACK_SH);
    }
}

__global__ void k_bfill(const int* __restrict__ s, const int* __restrict__ d,
                        int* __restrict__ u, int* __restrict__ be, int ne) {
    int half = ne >> 1;
    int idx = blockIdx.x * blockDim.x + threadIdx.x;
    int stride = gridDim.x * blockDim.x;
    for (; idx < half; idx += stride) {
        int d0 = d[idx], d1 = d[idx + half];
        int p0 = atomicAdd(&u[d0 >> BK_SH], 1);
        int p1 = atomicAdd(&u[d1 >> BK_SH], 1);
        be[p0] = s[idx] | ((d0 & 127) << PACK_SH);
        be[p1] = s[idx + half] | ((d1 & 127) << PACK_SH);
    }
}

// per-bucket: LDS count -> LDS scan -> coalesced off write -> L2-local csr scatter
__device__ __forceinline__ void bcsr_body(const int* __restrict__ bedge,
                                          const int* __restrict__ bbase,
                                          int* __restrict__ off, int* __restrict__ csr,
                                          int b, int nbkt, int ntot) {
    __shared__ int cnt[128], exs[128], sc[128];
    int t  = threadIdx.x;
    int e0 = bbase[b], e1 = bbase[b + 1];
    int node0 = b << BK_SH;
    int nloc  = ntot - node0; if (nloc > 128) nloc = 128;
    if (t < 128) cnt[t] = 0;
    __syncthreads();
    for (int e = e0 + t; e < e1; e += 256)
        atomicAdd(&cnt[(bedge[e] >> PACK_SH) & 127], 1);
    __syncthreads();
    int cv = (t < 128) ? cnt[t] : 0;
    if (t < 128) sc[t] = cv;
    __syncthreads();
    for (int o = 1; o < 128; o <<= 1) {
        int add = (t < 128 && t >= o) ? sc[t - o] : 0;
        __syncthreads();
        if (t < 128) sc[t] += add;
        __syncthreads();
    }
    if (t < 128) exs[t] = sc[t] - cv;
    __syncthreads();
    if (t < nloc) off[node0 + t] = e0 + exs[t];
    if (b == nbkt - 1 && t == 0) off[ntot] = e1;
    if (t < 128) cnt[t] = 0;
    __syncthreads();
    for (int e = e0 + t; e < e1; e += 256) {
        int p   = bedge[e];
        int dl  = (p >> PACK_SH) & 127;
        int pos = e0 + exs[dl] + atomicAdd(&cnt[dl], 1);
        csr[pos] = p & PACK_MASK;
    }
}

__global__ void __launch_bounds__(256) k_bcsr2(
    const int* beF, const int* bbF, int* offF, int* csrF,
    const int* beR, const int* bbR, int* offR, int* csrR, int nbkt, int ntot) {
    int b = blockIdx.x;
    if (b < nbkt) bcsr_body(beF, bbF, offF, csrF, b, nbkt, ntot);
    else          bcsr_body(beR, bbR, offR, csrR, b - nbkt, nbkt, ntot);
}

__global__ void __launch_bounds__(256) k_bcsr1(
    const int* be, const int* bb, int* off, int* csr, int nbkt, int ntot) {
    bcsr_body(be, bb, off, csr, blockIdx.x, nbkt, ntot);
}

// ---------------- sage kernels (unchanged from round 5) ----------------

__device__ __forceinline__ float seg_mean(const float* __restrict__ hin,
                                          const int* __restrict__ csr,
                                          int s0, int s1, int lane) {
    float a[8];
    #pragma unroll
    for (int k = 0; k < 8; ++k) a[k] = 0.f;
    for (int base = s0; base < s1; base += 32) {
        int e   = base + lane;
        int idx = csr[e < s1 ? e : s1 - 1];
        int m   = s1 - base; if (m > 32) m = 32;
        for (int j = 0; j < m; j += 8) {
            float v[8];
            #pragma unroll
            for (int k = 0; k < 8; ++k)
                v[k] = hin[__shfl(idx, (j + k) & 31, 32) * 32 + lane];
            #pragma unroll
            for (int k = 0; k < 8; ++k) {
                float w = (j + k < m) ? 1.f : 0.f;
                a[k] = fmaf(v[k], w, a[k]);
            }
        }
    }
    float s = ((a[0] + a[1]) + (a[2] + a[3])) + ((a[4] + a[5]) + (a[6] + a[7]));
    int c = s1 - s0;
    return s * (1.0f / (float)(c > 0 ? c : 1));
}

__device__ __forceinline__ void seg_mean_quad(
    const float* __restrict__ hin,
    const int* __restrict__ cA, int a0, int a1,
    const int* __restrict__ cB, int b0, int b1,
    const int* __restrict__ cC, int c0, int c1,
    const int* __restrict__ cD, int d0, int d1,
    int lane, float& oA, float& oB, float& oC, float& oD)
{
    float aA[4], aB[4], aC[4], aD[4];
    #pragma unroll
    for (int k = 0; k < 4; ++k) { aA[k] = 0.f; aB[k] = 0.f; aC[k] = 0.f; aD[k] = 0.f; }
    int pA = a0, pB = b0, pC = c0, pD = d0;
    while (pA < a1 || pB < b1 || pC < c1 || pD < d1) {
        int iA = 0, iB = 0, iC = 0, iD = 0, mA = 0, mB = 0, mC = 0, mD = 0;
        if (pA < a1) { int e = pA + lane; iA = cA[e < a1 ? e : a1 - 1]; mA = a1 - pA; if (mA > 32) mA = 32; }
        if (pB < b1) { int e = pB + lane; iB = cB[e < b1 ? e : b1 - 1]; mB = b1 - pB; if (mB > 32) mB = 32; }
        if (pC < c1) { int e = pC + lane; iC = cC[e < c1 ? e : c1 - 1]; mC = c1 - pC; if (mC > 32) mC = 32; }
        if (pD < d1) { int e = pD + lane; iD = cD[e < d1 ? e : d1 - 1]; mD = d1 - pD; if (mD > 32) mD = 32; }
        int mm = mA > mB ? mA : mB;
        if (mC > mm) mm = mC;
        if (mD > mm) mm = mD;
        for (int j = 0; j < mm; j += 8) {
            float vA[8], vB[8], vC[8], vD[8];
            bool dA = j < mA, dB = j < mB, dC = j < mC, dD = j < mD;
            if (dA) {
                #pragma unroll
                for (int k = 0; k < 8; ++k)
                    vA[k] = hin[__shfl(iA, (j + k) & 31, 32) * 32 + lane];
            }
            if (dB) {
                #pragma unroll
                for (int k = 0; k < 8; ++k)
                    vB[k] = hin[__shfl(iB, (j + k) & 31, 32) * 32 + lane];
            }
            if (dC) {
                #pragma unroll
                for (int k = 0; k < 8; ++k)
                    vC[k] = hin[__shfl(iC, (j + k) & 31, 32) * 32 + lane];
            }
            if (dD) {
                #pragma unroll
                for (int k = 0; k < 8; ++k)
                    vD[k] = hin[__shfl(iD, (j + k) & 31, 32) * 32 + lane];
            }
            if (dA) {
                #pragma unroll
                for (int k = 0; k < 8; ++k)
                    aA[k & 3] = fmaf(vA[k], (j + k < mA) ? 1.f : 0.f, aA[k & 3]);
            }
            if (dB) {
                #pragma unroll
                for (int k = 0; k < 8; ++k)
                    aB[k & 3] = fmaf(vB[k], (j + k < mB) ? 1.f : 0.f, aB[k & 3]);
            }
            if (dC) {
                #pragma unroll
                for (int k = 0; k < 8; ++k)
                    aC[k & 3] = fmaf(vC[k], (j + k < mC) ? 1.f : 0.f, aC[k & 3]);
            }
            if (dD) {
                #pragma unroll
                for (int k = 0; k < 8; ++k)
                    aD[k & 3] = fmaf(vD[k], (j + k < mD) ? 1.f : 0.f, aD[k & 3]);
            }
        }
        pA += 32; pB += 32; pC += 32; pD += 32;
    }
    int nA = a1 - a0, nB = b1 - b0, nC = c1 - c0, nD = d1 - d0;
    oA = ((aA[0] + aA[1]) + (aA[2] + aA[3])) * (1.0f / (float)(nA > 0 ? nA : 1));
    oB = ((aB[0] + aB[1]) + (aB[2] + aB[3])) * (1.0f / (float)(nB > 0 ? nB : 1));
    oC = ((aC[0] + aC[1]) + (aC[2] + aC[3])) * (1.0f / (float)(nC > 0 ? nC : 1));
    oD = ((aD[0] + aD[1]) + (aD[2] + aD[3])) * (1.0f / (float)(nD > 0 ? nD : 1));
}

__global__ void __launch_bounds__(256) k_sage(
    const float* __restrict__ hin, float* __restrict__ hout,
    const int* __restrict__ csr, const int* __restrict__ off,
    const float* __restrict__ wl, const float* __restrict__ bl, const float* __restrict__ wr,
    int n) {
    __shared__ float wlT[32][33];
    __shared__ float wrT[32][33];
    int tid = threadIdx.x;
    for (int idx = tid; idx < 1024; idx += 256) {
        int j = idx >> 5, k = idx & 31;
        wlT[k][j] = wl[idx];
        wrT[k][j] = wr[idx];
    }
    __syncthreads();
    int lane = tid & 31;
    int g    = blockIdx.x * 8 + (tid >> 5);
    int G    = gridDim.x * 8;
    for (int i = 4 * g; i < n; i += 4 * G) {
        int n0 = i, n1 = i + 1, n2 = i + 2, n3 = i + 3;
        float s0, s1, s2, s3;
        seg_mean_quad(hin, csr, off[n0], off[n0 + 1], csr, off[n1], off[n1 + 1],
                      csr, off[n2], off[n2 + 1], csr, off[n3], off[n3 + 1],
                      lane, s0, s1, s2, s3);
        float h0 = hin[n0 * 32 + lane];
        float h1 = hin[n1 * 32 + lane];
        float h2 = hin[n2 * 32 + lane];
        float h3 = hin[n3 * 32 + lane];
        float bb = bl[lane];
        float A0 = bb, A1 = bb, A2 = bb, A3 = bb;
        #pragma unroll
        for (int k = 0; k < 32; ++k) {
            float wlk = wlT[k][lane], wrk = wrT[k][lane];
            A0 = fmaf(__shfl(s0, k, 32), wlk, A0);
            A0 = fmaf(__shfl(h0, k, 32), wrk, A0);
            A1 = fmaf(__shfl(s1, k, 32), wlk, A1);
            A1 = fmaf(__shfl(h1, k, 32), wrk, A1);
            A2 = fmaf(__shfl(s2, k, 32), wlk, A2);
            A2 = fmaf(__shfl(h2, k, 32), wrk, A2);
            A3 = fmaf(__shfl(s3, k, 32), wlk, A3);
            A3 = fmaf(__shfl(h3, k, 32), wrk, A3);
        }
        hout[n0 * 32 + lane] = fmaxf(A0, 0.f);
        hout[n1 * 32 + lane] = fmaxf(A1, 0.f);
        hout[n2 * 32 + lane] = fmaxf(A2, 0.f);
        hout[n3 * 32 + lane] = fmaxf(A3, 0.f);
    }
}

__global__ void __launch_bounds__(256) k_sage2(
    const float* __restrict__ hin, float* __restrict__ hout,
    const int* __restrict__ csrF, const int* __restrict__ offF,
    const int* __restrict__ csrR, const int* __restrict__ offR,
    const float* __restrict__ wlF, const float* __restrict__ blF, const float* __restrict__ wrF,
    const float* __restrict__ wlR, const float* __restrict__ blR, const float* __restrict__ wrR,
    int n) {
    __shared__ float WLF[32][33], WRF[32][33], WLR[32][33], WRR[32][33];
    int tid = threadIdx.x;
    for (int idx = tid; idx < 1024; idx += 256) {
        int j = idx >> 5, k = idx & 31;
        WLF[k][j] = wlF[idx];
        WRF[k][j] = wrF[idx];
        WLR[k][j] = wlR[idx];
        WRR[k][j] = wrR[idx];
    }
    __syncthreads();
    int lane = tid & 31;
    int g    = blockIdx.x * 8 + (tid >> 5);
    int G    = gridDim.x * 8;
    for (int i = 2 * g; i < n; i += 2 * G) {
        int n0 = i, n1 = i + 1;
        float sF0, sR0, sF1, sR1;
        seg_mean_quad(hin, csrF, offF[n0], offF[n0 + 1], csrR, offR[n0], offR[n0 + 1],
                      csrF, offF[n1], offF[n1 + 1], csrR, offR[n1], offR[n1 + 1],
                      lane, sF0, sR0, sF1, sR1);
        float h0 = hin[n0 * 32 + lane];
        float h1 = hin[n1 * 32 + lane];
        float bF = blF[lane], bR = blR[lane];
        float aF0 = bF, aR0 = bR, aF1 = bF, aR1 = bR;
        #pragma unroll
        for (int k = 0; k < 32; ++k) {
            float f0 = __shfl(sF0, k, 32);
            float r0 = __shfl(sR0, k, 32);
            float f1 = __shfl(sF1, k, 32);
            float r1 = __shfl(sR1, k, 32);
            float hk0 = __shfl(h0, k, 32);
            float hk1 = __shfl(h1, k, 32);
            float wlf = WLF[k][lane], wrf = WRF[k][lane];
            float wlr = WLR[k][lane], wrr = WRR[k][lane];
            aF0 = fmaf(f0, wlf, aF0); aF0 = fmaf(hk0, wrf, aF0);
            aR0 = fmaf(r0, wlr, aR0); aR0 = fmaf(hk0, wrr, aR0);
            aF1 = fmaf(f1, wlf, aF1); aF1 = fmaf(hk1, wrf, aF1);
            aR1 = fmaf(r1, wlr, aR1); aR1 = fmaf(hk1, wrr, aR1);
        }
        hout[n0 * 32 + lane] = fmaxf(aF0, 0.f) + fmaxf(aR0, 0.f);
        hout[n1 * 32 + lane] = fmaxf(aF1, 0.f) + fmaxf(aR1, 0.f);
    }
}

__global__ void k_pair(const float* __restrict__ h, const int* __restrict__ pos1,
                       float* __restrict__ hp, int total) {
    int idx = blockIdx.x * blockDim.x + threadIdx.x;
    int stride = gridDim.x * blockDim.x;
    for (; idx < total; idx += stride) {
        int r = idx >> 5, k = idx & 31;
        int a = pos1[2 * r], b = pos1[2 * r + 1];
        hp[idx] = h[a * 32 + k] * h[b * 32 + k];
    }
}

__global__ void k_final(const float* __restrict__ h, const int* __restrict__ pos2,
                        const float* __restrict__ pw, const float* __restrict__ pb,
                        float* __restrict__ out, int m2) {
    int tid  = threadIdx.x;
    int lane = tid & 31;
    int i    = blockIdx.x * 8 + (tid >> 5);
    if (i >= m2) return;
    int p0 = pos2[2 * i], p1 = pos2[2 * i + 1];
    float v = h[p0 * 32 + lane] * h[p1 * 32 + lane] * pw[lane];
    #pragma unroll
    for (int o = 16; o > 0; o >>= 1) v += __shfl_xor(v, o, 32);
    if (lane == 0) out[i] = v + pb[0];
}

// ---------------- launch ----------------

extern "C" void kernel_launch(void* const* d_in, const int* in_sizes, int n_in,
                              void* d_out, int out_size, void* d_ws, size_t ws_size,
                              hipStream_t stream) {
    const int*   x      = (const int*)d_in[0];
    const int*   edge1  = (const int*)d_in[2];
    const int*   edge2  = (const int*)d_in[3];
    const int*   edge2r = (const int*)d_in[4];
    const int*   pos1   = (const int*)d_in[5];
    const int*   pos2   = (const int*)d_in[6];
    const float* emb    = (const float*)d_in[7];
    const float* gw     = (const float*)d_in[8];
    const float* gb     = (const float*)d_in[9];
    const float* gms    = (const float*)d_in[10];
    const float* c1wl   = (const float*)d_in[11];
    const float* c1bl   = (const float*)d_in[12];
    const float* c1wr   = (const float*)d_in[13];
    const float* c2wl   = (const float*)d_in[14];
    const float* c2bl   = (const float*)d_in[15];
    const float* c2wr   = (const float*)d_in[16];
    const float* c2rwl  = (const float*)d_in[17];
    const float* c2rbl  = (const float*)d_in[18];
    const float* c2rwr  = (const float*)d_in[19];
    const float* pw     = (const float*)d_in[20];
    const float* pb     = (const float*)d_in[21];
    float* out = (float*)d_out;

    char* ws = (char*)d_ws;
    float* hA    = (float*)(ws + OFF_HA);
    float* hB    = (float*)(ws + OFF_HB);
    int*   csr1  = (int*)(ws + OFF_CSR1);
    int*   csr2  = (int*)(ws + OFF_CSR2);
    int*   csr2r = (int*)(ws + OFF_CSR2R);
    int*   off1  = (int*)(ws + OFF_OFF1);
    int*   off2  = (int*)(ws + OFF_OFF2);
    int*   off2r = (int*)(ws + OFF_OFF2R);
    int*   bcntF = (int*)(ws + OFF_BC);
    int*   bbasF = bcntF + 2048;
    int*   bcurF = bcntF + 4096;
    int*   bcntR = bcntF + 6144;
    int*   bbasR = bcntF + 8192;
    int*   bcurR = bcntF + 10240;
    int*   bcnt1 = bcntF + 12288;
    int*   bbas1 = bcntF + 14336;
    int*   bcur1 = bcntF + 16384;
    float* stats = (float*)(ws + OFF_STATS);
    float* aff   = (float*)(ws + OFF_AFF);

    // temp bucketed-edge arrays overlay hA (dead until k_embed_stats)
    int* bedgeF = (int*)(ws + OFF_HA);
    int* bedgeR = (int*)(ws + OFF_HA + 12800000);
    int* bedge1 = (int*)(ws + OFF_HA);

    hipMemsetAsync(bcntF, 0, 73728, stream);
    hipMemsetAsync(stats, 0, 256, stream);

    // --- pair-graph CSR build (F and R fused) ---
    k_bcount2<<<4096, 256, 0, stream>>>(edge2 + E2N, bcntF, edge2r + E2N, bcntR, E2N);
    k_bcount<<<2048, 256, 0, stream>>>(edge1 + E1N, bcnt1, E1N);
    k_bscan3<<<3, 256, 0, stream>>>(bcntF, bbasF, bcurF, NBKT2,
                                    bcntR, bbasR, bcurR, NBKT2,
                                    bcnt1, bbas1, bcur1, NBKT1);
    k_bfill2<<<4096, 256, 0, stream>>>(edge2, edge2 + E2N, bcurF, bedgeF,
                                       edge2r, edge2r + E2N, bcurR, bedgeR, E2N);
    k_bcsr2<<<2 * NBKT2, 256, 0, stream>>>(bedgeF, bbasF, off2, csr2,
                                           bedgeR, bbasR, off2r, csr2r, NBKT2, N2N);

    // --- base-graph CSR build (reuses hA temp after k_bcsr2 drains) ---
    k_bfill<<<2048, 256, 0, stream>>>(edge1, edge1 + E1N, bcur1, bedge1, E1N);
    k_bcsr1<<<NBKT1, 256, 0, stream>>>(bedge1, bbas1, off1, csr1, NBKT1, NN);

    // --- embedding + GraphNorm ---
    k_embed_stats<<<1024, 256, 0, stream>>>(x, emb, hA, stats, NN);
    k_affine<<<1, 64, 0, stream>>>(stats, gw, gb, gms, aff, NN);
    k_apply_affine<<<2048, 256, 0, stream>>>(hA, aff, NN * 32);

    // --- conv1: hA -> hB(first half) -> hA   (csr1 in hB second half) ---
    k_sage<<<2048, 256, 0, stream>>>(hA, hB, csr1, off1, c1wl, c1bl, c1wr, NN);
    k_sage<<<2048, 256, 0, stream>>>(hB, hA, csr1, off1,
                                     c1wl + 1024, c1bl + 32, c1wr + 1024, NN);

    // --- pair features: hA (N rows) -> hB (N2 rows; csr1 now dead) ---
    k_pair<<<2048, 256, 0, stream>>>(hA, pos1, hB, N2N * 32);

    // --- conv2: hB -> hA -> hB (fused F+R each layer) ---
    k_sage2<<<2048, 256, 0, stream>>>(hB, hA, csr2, off2, csr2r, off2r,
        c2wl, c2bl, c2wr, c2rwl, c2rbl, c2rwr, N2N);
    k_sage2<<<2048, 256, 0, stream>>>(hA, hB, csr2, off2, csr2r, off2r,
        c2wl + 1024, c2bl + 32, c2wr + 1024, c2rwl + 1024, c2rbl + 32, c2rwr + 1024, N2N);

    // --- head ---
    k_final<<<(MN / 2) / 8, 256, 0, stream>>>(hB, pos2, pw, pb, out, MN / 2);
}

// Round 7
// 1023.154 us; speedup vs baseline: 3.2808x; 3.2808x over previous
//
#include <hip/hip_runtime.h>

#define LATENT 32
#define NN     100000
#define E1N    3200000
#define N2N    200000
#define E2N    3200000
#define MN     131072
#define EPSV   1e-5f

#define BK_SH     7          // 128 nodes per bucket
#define PACK_SH   20         // src in bits 0..19, dst_local in bits 20..26
#define PACK_MASK 0xFFFFF
#define NBKT1     782        // ceil(100000/128)
#define NBKT2     1563       // ceil(200000/128)
#define P_PART    128        // partitions per edge list
#define CH        25000      // edges per partition (3.2M / 128)
#define MF_       200064     // NBKT2*128
#define M1_       100096     // NBKT1*128
#define MTOT      500224     // 2*MF_ + M1_
#define SCAN_NB   245        // ceil(MTOT/2048)

// ---------------- workspace layout (bytes) ----------------
// hA [25.6MB] : pair h ping buffer; temp bucketed-edge storage during CSR build
// hB [25.6MB] : cnt array in first 4MB during build; csr1 in 2nd half until k_pair
constexpr size_t OFF_HA    = 0;
constexpr size_t OFF_HB    = 25600000;
constexpr size_t OFF_CSR1  = OFF_HB + 12800000;
constexpr size_t OFF_CSR2  = 51200000;
constexpr size_t OFF_CSR2R = 64000000;
constexpr size_t OFF_OFF1  = 76800000;
constexpr size_t OFF_OFF2  = OFF_OFF1 + 400128;
constexpr size_t OFF_OFF2R = OFF_OFF2 + 800128;
constexpr size_t OFF_BSUM  = OFF_OFF2R + 800128;
constexpr size_t OFF_STATS = OFF_BSUM + 2048;
constexpr size_t OFF_AFF   = OFF_STATS + 256;

// ---------------- embedding + GraphNorm ----------------

__global__ void k_embed_stats(const int* __restrict__ x, const float* __restrict__ emb,
                              float* __restrict__ h, float* __restrict__ stats, int n) {
    __shared__ float lsum[256], lsq[256];
    int tid = threadIdx.x;
    float s = 0.f, q = 0.f;
    int stride = gridDim.x * blockDim.x;
    for (int idx = blockIdx.x * blockDim.x + tid; idx < n * 32; idx += stride) {
        int i = idx >> 5, k = idx & 31;
        float v = emb[x[i] * 32 + k];
        h[idx] = v;
        s += v; q += v * v;
    }
    lsum[tid] = s; lsq[tid] = q;
    __syncthreads();
    if (tid < 32) {
        float ts = 0.f, tq = 0.f;
        #pragma unroll
        for (int r = 0; r < 8; ++r) { ts += lsum[tid + r * 32]; tq += lsq[tid + r * 32]; }
        atomicAdd(&stats[tid], ts);
        atomicAdd(&stats[32 + tid], tq);
    }
}

__global__ void k_affine(const float* __restrict__ stats, const float* __restrict__ w,
                         const float* __restrict__ b, const float* __restrict__ ms,
                         float* __restrict__ aff, int n) {
    int k = threadIdx.x;
    if (k < 32) {
        float mean = stats[k] / (float)n;
        float m2   = stats[32 + k] / (float)n;
        float m    = ms[k];
        float var  = m2 - 2.f * m * mean * mean + m * m * mean * mean;
        float A    = w[k] / sqrtf(var + EPSV);
        aff[k]      = A;
        aff[32 + k] = b[k] - A * m * mean;
    }
}

__global__ void k_apply_affine(float* __restrict__ h, const float* __restrict__ aff, int total) {
    int idx = blockIdx.x * blockDim.x + threadIdx.x;
    int stride = gridDim.x * blockDim.x;
    for (; idx < total; idx += stride) {
        int k = idx & 31;
        h[idx] = h[idx] * aff[k] + aff[32 + k];
    }
}

// ---------------- partitioned counting-sort CSR build ----------------

// one workgroup per (edge-list, partition); LDS histogram, zero global atomics
__global__ void __launch_bounds__(256) k_hist(const int* __restrict__ dF,
                                              const int* __restrict__ dR,
                                              const int* __restrict__ d1,
                                              int* __restrict__ cnt) {
    __shared__ int hist[NBKT2];
    int t = threadIdx.x;
    int which = blockIdx.x >> 7, p = blockIdx.x & 127;
    const int* d; int nbkt, roff;
    if (which == 0)      { d = dF; nbkt = NBKT2; roff = 0; }
    else if (which == 1) { d = dR; nbkt = NBKT2; roff = MF_; }
    else                 { d = d1; nbkt = NBKT1; roff = 2 * MF_; }
    for (int b = t; b < nbkt; b += 256) hist[b] = 0;
    __syncthreads();
    int e0 = p * CH;
    for (int e = e0 + t; e < e0 + CH; e += 256)
        atomicAdd(&hist[d[e] >> BK_SH], 1);
    __syncthreads();
    for (int b = t; b < nbkt; b += 256) cnt[roff + (b << 7) + p] = hist[b];
}

// flat exclusive scan of cnt[MTOT]: partial sums -> scan sums -> final
__global__ void k_scanA(const int* __restrict__ cnt, int* __restrict__ bsum) {
    __shared__ int lds[256];
    int t = threadIdx.x;
    int base = blockIdx.x * 2048 + t * 8;
    int s = 0;
    #pragma unroll
    for (int j = 0; j < 8; ++j) { int e = base + j; if (e < MTOT) s += cnt[e]; }
    lds[t] = s; __syncthreads();
    for (int o = 128; o > 0; o >>= 1) { if (t < o) lds[t] += lds[t + o]; __syncthreads(); }
    if (t == 0) bsum[blockIdx.x] = lds[0];
}

__global__ void k_scanB(int* __restrict__ bsum, int nb) {
    __shared__ int lds[256];
    int t = threadIdx.x;
    int v = (t < nb) ? bsum[t] : 0;
    lds[t] = v; __syncthreads();
    for (int o = 1; o < 256; o <<= 1) {
        int add = (t >= o) ? lds[t - o] : 0;
        __syncthreads();
        lds[t] += add;
        __syncthreads();
    }
    if (t < nb) bsum[t] = lds[t] - v;
}

__global__ void k_scanC(int* __restrict__ cnt, const int* __restrict__ bsum) {
    __shared__ int lds[256];
    int t = threadIdx.x;
    int base = blockIdx.x * 2048 + t * 8;
    int v[8]; int run = 0;
    #pragma unroll
    for (int j = 0; j < 8; ++j) {
        int e = base + j;
        v[j] = (e < MTOT) ? cnt[e] : 0;
        run += v[j];
    }
    int tot = run;
    lds[t] = tot; __syncthreads();
    for (int o = 1; o < 256; o <<= 1) {
        int add = (t >= o) ? lds[t - o] : 0;
        __syncthreads();
        lds[t] += add;
        __syncthreads();
    }
    int ex = lds[t] - tot + bsum[blockIdx.x];
    #pragma unroll
    for (int j = 0; j < 8; ++j) {
        int e = base + j;
        if (e < MTOT) { cnt[e] = ex; ex += v[j]; }
    }
}

// bin pass: LDS cursors (intra-workgroup atomics only), bucket-sorted packed writes
__global__ void __launch_bounds__(256) k_bfillFR(
    const int* __restrict__ sF, const int* __restrict__ dF,
    const int* __restrict__ sR, const int* __restrict__ dR,
    const int* __restrict__ cnt, int* __restrict__ beF, int* __restrict__ beR) {
    __shared__ int cur[NBKT2];
    int t = threadIdx.x;
    int which = blockIdx.x >> 7, p = blockIdx.x & 127;
    const int* s; const int* d; int* be; int roff, sub;
    if (which == 0) { s = sF; d = dF; be = beF; roff = 0;   sub = 0; }
    else            { s = sR; d = dR; be = beR; roff = MF_; sub = E2N; }
    for (int b = t; b < NBKT2; b += 256) cur[b] = cnt[roff + (b << 7) + p] - sub;
    __syncthreads();
    int e0 = p * CH;
    for (int e = e0 + t; e < e0 + CH; e += 256) {
        int dd  = d[e];
        int pos = atomicAdd(&cur[dd >> BK_SH], 1);
        be[pos] = s[e] | ((dd & 127) << PACK_SH);
    }
}

__global__ void __launch_bounds__(256) k_bfill1(
    const int* __restrict__ s1, const int* __restrict__ d1,
    const int* __restrict__ cnt, int* __restrict__ be) {
    __shared__ int cur[NBKT1];
    int t = threadIdx.x;
    int p = blockIdx.x;
    for (int b = t; b < NBKT1; b += 256) cur[b] = cnt[2 * MF_ + (b << 7) + p] - 2 * E2N;
    __syncthreads();
    int e0 = p * CH;
    for (int e = e0 + t; e < e0 + CH; e += 256) {
        int dd  = d1[e];
        int pos = atomicAdd(&cur[dd >> BK_SH], 1);
        be[pos] = s1[e] | ((dd & 127) << PACK_SH);
    }
}

// per-bucket: LDS count -> LDS scan -> coalesced off write -> L2-local csr scatter
__device__ __forceinline__ void bcsr_body(const int* __restrict__ bedge,
                                          const int* __restrict__ cnt, int roff, int sub,
                                          int* __restrict__ off, int* __restrict__ csr,
                                          int b, int nbkt, int ntot, int etot) {
    __shared__ int lcnt[128], exs[128], sc[128];
    int t  = threadIdx.x;
    int e0 = cnt[roff + (b << 7)] - sub;
    int e1 = (b + 1 < nbkt) ? cnt[roff + ((b + 1) << 7)] - sub : etot;
    int node0 = b << BK_SH;
    int nloc  = ntot - node0; if (nloc > 128) nloc = 128;
    if (t < 128) lcnt[t] = 0;
    __syncthreads();
    for (int e = e0 + t; e < e1; e += 256)
        atomicAdd(&lcnt[(bedge[e] >> PACK_SH) & 127], 1);
    __syncthreads();
    int cv = (t < 128) ? lcnt[t] : 0;
    if (t < 128) sc[t] = cv;
    __syncthreads();
    for (int o = 1; o < 128; o <<= 1) {
        int add = (t < 128 && t >= o) ? sc[t - o] : 0;
        __syncthreads();
        if (t < 128) sc[t] += add;
        __syncthreads();
    }
    if (t < 128) exs[t] = sc[t] - cv;
    __syncthreads();
    if (t < nloc) off[node0 + t] = e0 + exs[t];
    if (b == nbkt - 1 && t == 0) off[ntot] = e1;
    if (t < 128) lcnt[t] = 0;
    __syncthreads();
    for (int e = e0 + t; e < e1; e += 256) {
        int p   = bedge[e];
        int dl  = (p >> PACK_SH) & 127;
        int pos = e0 + exs[dl] + atomicAdd(&lcnt[dl], 1);
        csr[pos] = p & PACK_MASK;
    }
}

__global__ void __launch_bounds__(256) k_bcsr2(
    const int* beF, const int* beR, const int* __restrict__ cnt,
    int* offF, int* csrF, int* offR, int* csrR) {
    int b = blockIdx.x;
    if (b < NBKT2) bcsr_body(beF, cnt, 0,   0,   offF, csrF, b,         NBKT2, N2N, E2N);
    else           bcsr_body(beR, cnt, MF_, E2N, offR, csrR, b - NBKT2, NBKT2, N2N, E2N);
}

__global__ void __launch_bounds__(256) k_bcsr1(
    const int* be, const int* __restrict__ cnt, int* off, int* csr) {
    bcsr_body(be, cnt, 2 * MF_, 2 * E2N, off, csr, blockIdx.x, NBKT1, NN, E1N);
}

// ---------------- sage kernels ----------------

__device__ __forceinline__ void seg_mean_quad(
    const float* __restrict__ hin,
    const int* __restrict__ cA, int a0, int a1,
    const int* __restrict__ cB, int b0, int b1,
    const int* __restrict__ cC, int c0, int c1,
    const int* __restrict__ cD, int d0, int d1,
    int lane, float& oA, float& oB, float& oC, float& oD)
{
    float aA[4], aB[4], aC[4], aD[4];
    #pragma unroll
    for (int k = 0; k < 4; ++k) { aA[k] = 0.f; aB[k] = 0.f; aC[k] = 0.f; aD[k] = 0.f; }
    int pA = a0, pB = b0, pC = c0, pD = d0;
    while (pA < a1 || pB < b1 || pC < c1 || pD < d1) {
        int iA = 0, iB = 0, iC = 0, iD = 0, mA = 0, mB = 0, mC = 0, mD = 0;
        if (pA < a1) { int e = pA + lane; iA = cA[e < a1 ? e : a1 - 1]; mA = a1 - pA; if (mA > 32) mA = 32; }
        if (pB < b1) { int e = pB + lane; iB = cB[e < b1 ? e : b1 - 1]; mB = b1 - pB; if (mB > 32) mB = 32; }
        if (pC < c1) { int e = pC + lane; iC = cC[e < c1 ? e : c1 - 1]; mC = c1 - pC; if (mC > 32) mC = 32; }
        if (pD < d1) { int e = pD + lane; iD = cD[e < d1 ? e : d1 - 1]; mD = d1 - pD; if (mD > 32) mD = 32; }
        int mm = mA > mB ? mA : mB;
        if (mC > mm) mm = mC;
        if (mD > mm) mm = mD;
        for (int j = 0; j < mm; j += 8) {
            float vA[8], vB[8], vC[8], vD[8];
            bool dA = j < mA, dB = j < mB, dC = j < mC, dD = j < mD;
            if (dA) {
                #pragma unroll
                for (int k = 0; k < 8; ++k)
                    vA[k] = hin[__shfl(iA, (j + k) & 31, 32) * 32 + lane];
            }
            if (dB) {
                #pragma unroll
                for (int k = 0; k < 8; ++k)
                    vB[k] = hin[__shfl(iB, (j + k) & 31, 32) * 32 + lane];
            }
            if (dC) {
                #pragma unroll
                for (int k = 0; k < 8; ++k)
                    vC[k] = hin[__shfl(iC, (j + k) & 31, 32) * 32 + lane];
            }
            if (dD) {
                #pragma unroll
                for (int k = 0; k < 8; ++k)
                    vD[k] = hin[__shfl(iD, (j + k) & 31, 32) * 32 + lane];
            }
            if (dA) {
                #pragma unroll
                for (int k = 0; k < 8; ++k)
                    aA[k & 3] = fmaf(vA[k], (j + k < mA) ? 1.f : 0.f, aA[k & 3]);
            }
            if (dB) {
                #pragma unroll
                for (int k = 0; k < 8; ++k)
                    aB[k & 3] = fmaf(vB[k], (j + k < mB) ? 1.f : 0.f, aB[k & 3]);
            }
            if (dC) {
                #pragma unroll
                for (int k = 0; k < 8; ++k)
                    aC[k & 3] = fmaf(vC[k], (j + k < mC) ? 1.f : 0.f, aC[k & 3]);
            }
            if (dD) {
                #pragma unroll
                for (int k = 0; k < 8; ++k)
                    aD[k & 3] = fmaf(vD[k], (j + k < mD) ? 1.f : 0.f, aD[k & 3]);
            }
        }
        pA += 32; pB += 32; pC += 32; pD += 32;
    }
    int nA = a1 - a0, nB = b1 - b0, nC = c1 - c0, nD = d1 - d0;
    oA = ((aA[0] + aA[1]) + (aA[2] + aA[3])) * (1.0f / (float)(nA > 0 ? nA : 1));
    oB = ((aB[0] + aB[1]) + (aB[2] + aB[3])) * (1.0f / (float)(nB > 0 ? nB : 1));
    oC = ((aC[0] + aC[1]) + (aC[2] + aC[3])) * (1.0f / (float)(nC > 0 ? nC : 1));
    oD = ((aD[0] + aD[1]) + (aD[2] + aD[3])) * (1.0f / (float)(nD > 0 ? nD : 1));
}

__global__ void __launch_bounds__(256) k_sage(
    const float* __restrict__ hin, float* __restrict__ hout,
    const int* __restrict__ csr, const int* __restrict__ off,
    const float* __restrict__ wl, const float* __restrict__ bl, const float* __restrict__ wr,
    int n) {
    __shared__ float wlT[32][33];
    __shared__ float wrT[32][33];
    int tid = threadIdx.x;
    for (int idx = tid; idx < 1024; idx += 256) {
        int j = idx >> 5, k = idx & 31;
        wlT[k][j] = wl[idx];
        wrT[k][j] = wr[idx];
    }
    __syncthreads();
    int lane = tid & 31;
    int g    = blockIdx.x * 8 + (tid >> 5);
    int G    = gridDim.x * 8;
    for (int i = 4 * g; i < n; i += 4 * G) {
        int n0 = i, n1 = i + 1, n2 = i + 2, n3 = i + 3;
        float s0, s1, s2, s3;
        seg_mean_quad(hin, csr, off[n0], off[n0 + 1], csr, off[n1], off[n1 + 1],
                      csr, off[n2], off[n2 + 1], csr, off[n3], off[n3 + 1],
                      lane, s0, s1, s2, s3);
        float h0 = hin[n0 * 32 + lane];
        float h1 = hin[n1 * 32 + lane];
        float h2 = hin[n2 * 32 + lane];
        float h3 = hin[n3 * 32 + lane];
        float bb = bl[lane];
        float A0 = bb, A1 = bb, A2 = bb, A3 = bb;
        #pragma unroll
        for (int k = 0; k < 32; ++k) {
            float wlk = wlT[k][lane], wrk = wrT[k][lane];
            A0 = fmaf(__shfl(s0, k, 32), wlk, A0);
            A0 = fmaf(__shfl(h0, k, 32), wrk, A0);
            A1 = fmaf(__shfl(s1, k, 32), wlk, A1);
            A1 = fmaf(__shfl(h1, k, 32), wrk, A1);
            A2 = fmaf(__shfl(s2, k, 32), wlk, A2);
            A2 = fmaf(__shfl(h2, k, 32), wrk, A2);
            A3 = fmaf(__shfl(s3, k, 32), wlk, A3);
            A3 = fmaf(__shfl(h3, k, 32), wrk, A3);
        }
        hout[n0 * 32 + lane] = fmaxf(A0, 0.f);
        hout[n1 * 32 + lane] = fmaxf(A1, 0.f);
        hout[n2 * 32 + lane] = fmaxf(A2, 0.f);
        hout[n3 * 32 + lane] = fmaxf(A3, 0.f);
    }
}

__global__ void __launch_bounds__(256) k_sage2(
    const float* __restrict__ hin, float* __restrict__ hout,
    const int* __restrict__ csrF, const int* __restrict__ offF,
    const int* __restrict__ csrR, const int* __restrict__ offR,
    const float* __restrict__ wlF, const float* __restrict__ blF, const float* __restrict__ wrF,
    const float* __restrict__ wlR, const float* __restrict__ blR, const float* __restrict__ wrR,
    int n) {
    __shared__ float WLF[32][33], WRF[32][33], WLR[32][33], WRR[32][33];
    int tid = threadIdx.x;
    for (int idx = tid; idx < 1024; idx += 256) {
        int j = idx >> 5, k = idx & 31;
        WLF[k][j] = wlF[idx];
        WRF[k][j] = wrF[idx];
        WLR[k][j] = wlR[idx];
        WRR[k][j] = wrR[idx];
    }
    __syncthreads();
    int lane = tid & 31;
    int g    = blockIdx.x * 8 + (tid >> 5);
    int G    = gridDim.x * 8;
    for (int i = 2 * g; i < n; i += 2 * G) {
        int n0 = i, n1 = i + 1;
        float sF0, sR0, sF1, sR1;
        seg_mean_quad(hin, csrF, offF[n0], offF[n0 + 1], csrR, offR[n0], offR[n0 + 1],
                      csrF, offF[n1], offF[n1 + 1], csrR, offR[n1], offR[n1 + 1],
                      lane, sF0, sR0, sF1, sR1);
        float h0 = hin[n0 * 32 + lane];
        float h1 = hin[n1 * 32 + lane];
        float bF = blF[lane], bR = blR[lane];
        float aF0 = bF, aR0 = bR, aF1 = bF, aR1 = bR;
        #pragma unroll
        for (int k = 0; k < 32; ++k) {
            float f0 = __shfl(sF0, k, 32);
            float r0 = __shfl(sR0, k, 32);
            float f1 = __shfl(sF1, k, 32);
            float r1 = __shfl(sR1, k, 32);
            float hk0 = __shfl(h0, k, 32);
            float hk1 = __shfl(h1, k, 32);
            float wlf = WLF[k][lane], wrf = WRF[k][lane];
            float wlr = WLR[k][lane], wrr = WRR[k][lane];
            aF0 = fmaf(f0, wlf, aF0); aF0 = fmaf(hk0, wrf, aF0);
            aR0 = fmaf(r0, wlr, aR0); aR0 = fmaf(hk0, wrr, aR0);
            aF1 = fmaf(f1, wlf, aF1); aF1 = fmaf(hk1, wrf, aF1);
            aR1 = fmaf(r1, wlr, aR1); aR1 = fmaf(hk1, wrr, aR1);
        }
        hout[n0 * 32 + lane] = fmaxf(aF0, 0.f) + fmaxf(aR0, 0.f);
        hout[n1 * 32 + lane] = fmaxf(aF1, 0.f) + fmaxf(aR1, 0.f);
    }
}

__global__ void k_pair(const float* __restrict__ h, const int* __restrict__ pos1,
                       float* __restrict__ hp, int total) {
    int idx = blockIdx.x * blockDim.x + threadIdx.x;
    int stride = gridDim.x * blockDim.x;
    for (; idx < total; idx += stride) {
        int r = idx >> 5, k = idx & 31;
        int a = pos1[2 * r], b = pos1[2 * r + 1];
        hp[idx] = h[a * 32 + k] * h[b * 32 + k];
    }
}

__global__ void k_final(const float* __restrict__ h, const int* __restrict__ pos2,
                        const float* __restrict__ pw, const float* __restrict__ pb,
                        float* __restrict__ out, int m2) {
    int tid  = threadIdx.x;
    int lane = tid & 31;
    int i    = blockIdx.x * 8 + (tid >> 5);
    if (i >= m2) return;
    int p0 = pos2[2 * i], p1 = pos2[2 * i + 1];
    float v = h[p0 * 32 + lane] * h[p1 * 32 + lane] * pw[lane];
    #pragma unroll
    for (int o = 16; o > 0; o >>= 1) v += __shfl_xor(v, o, 32);
    if (lane == 0) out[i] = v + pb[0];
}

// ---------------- launch ----------------

extern "C" void kernel_launch(void* const* d_in, const int* in_sizes, int n_in,
                              void* d_out, int out_size, void* d_ws, size_t ws_size,
                              hipStream_t stream) {
    const int*   x      = (const int*)d_in[0];
    const int*   edge1  = (const int*)d_in[2];
    const int*   edge2  = (const int*)d_in[3];
    const int*   edge2r = (const int*)d_in[4];
    const int*   pos1   = (const int*)d_in[5];
    const int*   pos2   = (const int*)d_in[6];
    const float* emb    = (const float*)d_in[7];
    const float* gw     = (const float*)d_in[8];
    const float* gb     = (const float*)d_in[9];
    const float* gms    = (const float*)d_in[10];
    const float* c1wl   = (const float*)d_in[11];
    const float* c1bl   = (const float*)d_in[12];
    const float* c1wr   = (const float*)d_in[13];
    const float* c2wl   = (const float*)d_in[14];
    const float* c2bl   = (const float*)d_in[15];
    const float* c2wr   = (const float*)d_in[16];
    const float* c2rwl  = (const float*)d_in[17];
    const float* c2rbl  = (const float*)d_in[18];
    const float* c2rwr  = (const float*)d_in[19];
    const float* pw     = (const float*)d_in[20];
    const float* pb     = (const float*)d_in[21];
    float* out = (float*)d_out;

    char* ws = (char*)d_ws;
    float* hA    = (float*)(ws + OFF_HA);
    float* hB    = (float*)(ws + OFF_HB);
    int*   cnt   = (int*)(ws + OFF_HB);          // 2MB region of hB, dead before k_sage
    int*   csr1  = (int*)(ws + OFF_CSR1);
    int*   csr2  = (int*)(ws + OFF_CSR2);
    int*   csr2r = (int*)(ws + OFF_CSR2R);
    int*   off1  = (int*)(ws + OFF_OFF1);
    int*   off2  = (int*)(ws + OFF_OFF2);
    int*   off2r = (int*)(ws + OFF_OFF2R);
    int*   bsum  = (int*)(ws + OFF_BSUM);
    float* stats = (float*)(ws + OFF_STATS);
    float* aff   = (float*)(ws + OFF_AFF);

    // temp bucketed-edge arrays overlay hA (dead until k_embed_stats)
    int* beF = (int*)(ws + OFF_HA);
    int* beR = (int*)(ws + OFF_HA + 12800000);
    int* be1 = (int*)(ws + OFF_HA);

    hipMemsetAsync(stats, 0, 256, stream);

    // --- CSR build: histogram -> scan -> bin (LDS cursors) -> per-bucket refine ---
    k_hist<<<3 * P_PART, 256, 0, stream>>>(edge2 + E2N, edge2r + E2N, edge1 + E1N, cnt);
    k_scanA<<<SCAN_NB, 256, 0, stream>>>(cnt, bsum);
    k_scanB<<<1, 256, 0, stream>>>(bsum, SCAN_NB);
    k_scanC<<<SCAN_NB, 256, 0, stream>>>(cnt, bsum);
    k_bfillFR<<<2 * P_PART, 256, 0, stream>>>(edge2, edge2 + E2N, edge2r, edge2r + E2N,
                                              cnt, beF, beR);
    k_bcsr2<<<2 * NBKT2, 256, 0, stream>>>(beF, beR, cnt, off2, csr2, off2r, csr2r);
    k_bfill1<<<P_PART, 256, 0, stream>>>(edge1, edge1 + E1N, cnt, be1);
    k_bcsr1<<<NBKT1, 256, 0, stream>>>(be1, cnt, off1, csr1);

    // --- embedding + GraphNorm ---
    k_embed_stats<<<1024, 256, 0, stream>>>(x, emb, hA, stats, NN);
    k_affine<<<1, 64, 0, stream>>>(stats, gw, gb, gms, aff, NN);
    k_apply_affine<<<2048, 256, 0, stream>>>(hA, aff, NN * 32);

    // --- conv1: hA -> hB(first half; clobbers cnt, now dead) -> hA ---
    k_sage<<<2048, 256, 0, stream>>>(hA, hB, csr1, off1, c1wl, c1bl, c1wr, NN);
    k_sage<<<2048, 256, 0, stream>>>(hB, hA, csr1, off1,
                                     c1wl + 1024, c1bl + 32, c1wr + 1024, NN);

    // --- pair features: hA (N rows) -> hB (N2 rows; csr1 now dead) ---
    k_pair<<<2048, 256, 0, stream>>>(hA, pos1, hB, N2N * 32);

    // --- conv2: hB -> hA -> hB (fused F+R each layer) ---
    k_sage2<<<2048, 256, 0, stream>>>(hB, hA, csr2, off2, csr2r, off2r,
        c2wl, c2bl, c2wr, c2rwl, c2rbl, c2rwr, N2N);
    k_sage2<<<2048, 256, 0, stream>>>(hA, hB, csr2, off2, csr2r, off2r,
        c2wl + 1024, c2bl + 32, c2wr + 1024, c2rwl + 1024, c2rbl + 32, c2rwr + 1024, N2N);

    // --- head ---
    k_final<<<(MN / 2) / 8, 256, 0, stream>>>(hB, pos2, pw, pb, out, MN / 2);
}

// Round 8
// 967.323 us; speedup vs baseline: 3.4701x; 1.0577x over previous
//
#include <hip/hip_runtime.h>

#define LATENT 32
#define NN     100000
#define E1N    3200000
#define N2N    200000
#define E2N    3200000
#define MN     131072
#define MAXX   100
#define EPSV   1e-5f

#define BK_SH     7          // 128 nodes per bucket
#define PACK_SH   20         // src in bits 0..19, dst_local in bits 20..26
#define PACK_MASK 0xFFFFF
#define NBKT1     782        // ceil(100000/128)
#define NBKT2     1563       // ceil(200000/128)
#define P_PART    128        // partitions per edge list
#define CH        25000      // edges per partition (3.2M / 128)
#define MF_       200064     // NBKT2*128
#define M1_       100096     // NBKT1*128
#define MTOT      500224     // 2*MF_ + M1_
#define SCAN_NB   245        // ceil(MTOT/2048)

// ---------------- workspace layout (bytes) ----------------
constexpr size_t OFF_HA    = 0;
constexpr size_t OFF_HB    = 25600000;
constexpr size_t OFF_CSR1  = OFF_HB + 12800000;
constexpr size_t OFF_CSR2  = 51200000;
constexpr size_t OFF_CSR2R = 64000000;
constexpr size_t OFF_OFF1  = 76800000;
constexpr size_t OFF_OFF2  = OFF_OFF1 + 400128;
constexpr size_t OFF_OFF2R = OFF_OFF2 + 800128;
constexpr size_t OFF_BSUM  = OFF_OFF2R + 800128;
constexpr size_t OFF_HIST  = OFF_BSUM + 2048;     // 128 ints
constexpr size_t OFF_WLP   = OFF_HIST + 512;      // 1024 f
constexpr size_t OFF_WRP   = OFF_WLP + 4096;      // 1024 f
constexpr size_t OFF_BP    = OFF_WRP + 4096;      // 32 f

// ---------------- x histogram + fused GraphNorm/weight prep ----------------

__global__ void k_histx(const int* __restrict__ x, int* __restrict__ hist, int n) {
    __shared__ int h[128];
    int t = threadIdx.x;
    if (t < 128) h[t] = 0;
    __syncthreads();
    int stride = gridDim.x * blockDim.x;
    for (int i = blockIdx.x * blockDim.x + t; i < n; i += stride)
        atomicAdd(&h[x[i]], 1);
    __syncthreads();
    if (t < 128 && h[t] > 0) atomicAdd(&hist[t], h[t]);
}

// A,B from exact histogram stats; fold into layer-1 weights
__global__ void k_prep(const int* __restrict__ hist, const float* __restrict__ emb,
                       const float* __restrict__ gw, const float* __restrict__ gb,
                       const float* __restrict__ gms,
                       const float* __restrict__ wl, const float* __restrict__ bl,
                       const float* __restrict__ wr,
                       float* __restrict__ wlp, float* __restrict__ wrp,
                       float* __restrict__ bp) {
    __shared__ float A[32], B[32];
    int t = threadIdx.x;
    if (t < 32) {
        float m = 0.f, q = 0.f;
        for (int c = 0; c <= MAXX; ++c) {
            float hc = (float)hist[c];
            float v  = emb[c * 32 + t];
            m += hc * v; q += hc * v * v;
        }
        m *= (1.f / (float)NN); q *= (1.f / (float)NN);
        float ms  = gms[t];
        float var = q - 2.f * ms * m * m + ms * ms * m * m;
        float a   = gw[t] / sqrtf(var + EPSV);
        A[t] = a;
        B[t] = gb[t] - a * ms * m;
    }
    __syncthreads();
    for (int i = t; i < 1024; i += 256) {
        int k = i & 31;
        wlp[i] = wl[i] * A[k];
        wrp[i] = wr[i] * A[k];
    }
    if (t < 32) {
        float s = bl[t];
        for (int k = 0; k < 32; ++k) s += (wl[t * 32 + k] + wr[t * 32 + k]) * B[k];
        bp[t] = s;
    }
}

// ---------------- partitioned counting-sort CSR build ----------------

__global__ void __launch_bounds__(256) k_hist(const int* __restrict__ dF,
                                              const int* __restrict__ dR,
                                              const int* __restrict__ d1,
                                              int* __restrict__ cnt) {
    __shared__ int hist[NBKT2];
    int t = threadIdx.x;
    int which = blockIdx.x >> 7, p = blockIdx.x & 127;
    const int* d; int nbkt, roff;
    if (which == 0)      { d = dF; nbkt = NBKT2; roff = 0; }
    else if (which == 1) { d = dR; nbkt = NBKT2; roff = MF_; }
    else                 { d = d1; nbkt = NBKT1; roff = 2 * MF_; }
    for (int b = t; b < nbkt; b += 256) hist[b] = 0;
    __syncthreads();
    int e0 = p * CH;
    for (int e = e0 + t; e < e0 + CH; e += 256)
        atomicAdd(&hist[d[e] >> BK_SH], 1);
    __syncthreads();
    for (int b = t; b < nbkt; b += 256) cnt[roff + (b << 7) + p] = hist[b];
}

__global__ void k_scanA(const int* __restrict__ cnt, int* __restrict__ bsum) {
    __shared__ int lds[256];
    int t = threadIdx.x;
    int base = blockIdx.x * 2048 + t * 8;
    int s = 0;
    #pragma unroll
    for (int j = 0; j < 8; ++j) { int e = base + j; if (e < MTOT) s += cnt[e]; }
    lds[t] = s; __syncthreads();
    for (int o = 128; o > 0; o >>= 1) { if (t < o) lds[t] += lds[t + o]; __syncthreads(); }
    if (t == 0) bsum[blockIdx.x] = lds[0];
}

__global__ void k_scanB(int* __restrict__ bsum, int nb) {
    __shared__ int lds[256];
    int t = threadIdx.x;
    int v = (t < nb) ? bsum[t] : 0;
    lds[t] = v; __syncthreads();
    for (int o = 1; o < 256; o <<= 1) {
        int add = (t >= o) ? lds[t - o] : 0;
        __syncthreads();
        lds[t] += add;
        __syncthreads();
    }
    if (t < nb) bsum[t] = lds[t] - v;
}

__global__ void k_scanC(int* __restrict__ cnt, const int* __restrict__ bsum) {
    __shared__ int lds[256];
    int t = threadIdx.x;
    int base = blockIdx.x * 2048 + t * 8;
    int v[8]; int run = 0;
    #pragma unroll
    for (int j = 0; j < 8; ++j) {
        int e = base + j;
        v[j] = (e < MTOT) ? cnt[e] : 0;
        run += v[j];
    }
    int tot = run;
    lds[t] = tot; __syncthreads();
    for (int o = 1; o < 256; o <<= 1) {
        int add = (t >= o) ? lds[t - o] : 0;
        __syncthreads();
        lds[t] += add;
        __syncthreads();
    }
    int ex = lds[t] - tot + bsum[blockIdx.x];
    #pragma unroll
    for (int j = 0; j < 8; ++j) {
        int e = base + j;
        if (e < MTOT) { cnt[e] = ex; ex += v[j]; }
    }
}

__global__ void __launch_bounds__(256) k_bfillFR(
    const int* __restrict__ sF, const int* __restrict__ dF,
    const int* __restrict__ sR, const int* __restrict__ dR,
    const int* __restrict__ cnt, int* __restrict__ beF, int* __restrict__ beR) {
    __shared__ int cur[NBKT2];
    int t = threadIdx.x;
    int which = blockIdx.x >> 7, p = blockIdx.x & 127;
    const int* s; const int* d; int* be; int roff, sub;
    if (which == 0) { s = sF; d = dF; be = beF; roff = 0;   sub = 0; }
    else            { s = sR; d = dR; be = beR; roff = MF_; sub = E2N; }
    for (int b = t; b < NBKT2; b += 256) cur[b] = cnt[roff + (b << 7) + p] - sub;
    __syncthreads();
    int e0 = p * CH;
    for (int e = e0 + t; e < e0 + CH; e += 256) {
        int dd  = d[e];
        int pos = atomicAdd(&cur[dd >> BK_SH], 1);
        be[pos] = s[e] | ((dd & 127) << PACK_SH);
    }
}

__global__ void __launch_bounds__(256) k_bfill1(
    const int* __restrict__ s1, const int* __restrict__ d1,
    const int* __restrict__ cnt, int* __restrict__ be) {
    __shared__ int cur[NBKT1];
    int t = threadIdx.x;
    int p = blockIdx.x;
    for (int b = t; b < NBKT1; b += 256) cur[b] = cnt[2 * MF_ + (b << 7) + p] - 2 * E2N;
    __syncthreads();
    int e0 = p * CH;
    for (int e = e0 + t; e < e0 + CH; e += 256) {
        int dd  = d1[e];
        int pos = atomicAdd(&cur[dd >> BK_SH], 1);
        be[pos] = s1[e] | ((dd & 127) << PACK_SH);
    }
}

__device__ __forceinline__ void bcsr_body(const int* __restrict__ bedge,
                                          const int* __restrict__ cnt, int roff, int sub,
                                          int* __restrict__ off, int* __restrict__ csr,
                                          int b, int nbkt, int ntot, int etot) {
    __shared__ int lcnt[128], exs[128], sc[128];
    int t  = threadIdx.x;
    int e0 = cnt[roff + (b << 7)] - sub;
    int e1 = (b + 1 < nbkt) ? cnt[roff + ((b + 1) << 7)] - sub : etot;
    int node0 = b << BK_SH;
    int nloc  = ntot - node0; if (nloc > 128) nloc = 128;
    if (t < 128) lcnt[t] = 0;
    __syncthreads();
    for (int e = e0 + t; e < e1; e += 256)
        atomicAdd(&lcnt[(bedge[e] >> PACK_SH) & 127], 1);
    __syncthreads();
    int cv = (t < 128) ? lcnt[t] : 0;
    if (t < 128) sc[t] = cv;
    __syncthreads();
    for (int o = 1; o < 128; o <<= 1) {
        int add = (t < 128 && t >= o) ? sc[t - o] : 0;
        __syncthreads();
        if (t < 128) sc[t] += add;
        __syncthreads();
    }
    if (t < 128) exs[t] = sc[t] - cv;
    __syncthreads();
    if (t < nloc) off[node0 + t] = e0 + exs[t];
    if (b == nbkt - 1 && t == 0) off[ntot] = e1;
    if (t < 128) lcnt[t] = 0;
    __syncthreads();
    for (int e = e0 + t; e < e1; e += 256) {
        int p   = bedge[e];
        int dl  = (p >> PACK_SH) & 127;
        int pos = e0 + exs[dl] + atomicAdd(&lcnt[dl], 1);
        csr[pos] = p & PACK_MASK;
    }
}

__global__ void __launch_bounds__(256) k_bcsr2(
    const int* beF, const int* beR, const int* __restrict__ cnt,
    int* offF, int* csrF, int* offR, int* csrR) {
    int b = blockIdx.x;
    if (b < NBKT2) bcsr_body(beF, cnt, 0,   0,   offF, csrF, b,         NBKT2, N2N, E2N);
    else           bcsr_body(beR, cnt, MF_, E2N, offR, csrR, b - NBKT2, NBKT2, N2N, E2N);
}

__global__ void __launch_bounds__(256) k_bcsr1(
    const int* be, const int* __restrict__ cnt, int* off, int* csr) {
    bcsr_body(be, cnt, 2 * MF_, 2 * E2N, off, csr, blockIdx.x, NBKT1, NN, E1N);
}

// ---------------- conv1 layer 1: LDS emb table, 4B x-gathers ----------------

__global__ void __launch_bounds__(256) k_sage_emb(
    const int* __restrict__ x, const float* __restrict__ emb,
    float* __restrict__ hout,
    const int* __restrict__ csr, const int* __restrict__ off,
    const float* __restrict__ wlp, const float* __restrict__ bp,
    const float* __restrict__ wrp, int n) {
    __shared__ float embS[(MAXX + 1) * 32];
    __shared__ float wlT[32][33];
    __shared__ float wrT[32][33];
    int tid = threadIdx.x;
    for (int i = tid; i < (MAXX + 1) * 32; i += 256) embS[i] = emb[i];
    for (int i = tid; i < 1024; i += 256) {
        int j = i >> 5, k = i & 31;
        wlT[k][j] = wlp[i];
        wrT[k][j] = wrp[i];
    }
    __syncthreads();
    int lane = tid & 31;
    int g    = blockIdx.x * 8 + (tid >> 5);
    int G    = gridDim.x * 8;
    for (int node = g; node < n; node += G) {
        int s0 = off[node], s1 = off[node + 1];
        float a0 = 0.f, a1 = 0.f, a2 = 0.f, a3 = 0.f;
        for (int base = s0; base < s1; base += 32) {
            int e  = base + lane;
            int xv = x[csr[e < s1 ? e : s1 - 1]];
            int m  = s1 - base; if (m > 32) m = 32;
            for (int j = 0; j < m; j += 4) {
                #pragma unroll
                for (int k = 0; k < 4; ++k) {
                    int jj = j + k;
                    int xj = __shfl(xv, jj & 31, 32);
                    float v = embS[xj * 32 + lane];
                    float w = (jj < m) ? 1.f : 0.f;
                    switch (k) {
                        case 0: a0 = fmaf(v, w, a0); break;
                        case 1: a1 = fmaf(v, w, a1); break;
                        case 2: a2 = fmaf(v, w, a2); break;
                        case 3: a3 = fmaf(v, w, a3); break;
                    }
                }
            }
        }
        int c = s1 - s0;
        float s = ((a0 + a1) + (a2 + a3)) * (1.0f / (float)(c > 0 ? c : 1));
        float hs = embS[x[node] * 32 + lane];
        float acc = bp[lane];
        #pragma unroll
        for (int k = 0; k < 32; ++k) {
            acc = fmaf(__shfl(s, k, 32), wlT[k][lane], acc);
            acc = fmaf(__shfl(hs, k, 32), wrT[k][lane], acc);
        }
        hout[node * 32 + lane] = fmaxf(acc, 0.f);
    }
}

// ---------------- sage kernels ----------------

__device__ __forceinline__ void seg_mean_quad(
    const float* __restrict__ hin,
    const int* __restrict__ cA, int a0, int a1,
    const int* __restrict__ cB, int b0, int b1,
    const int* __restrict__ cC, int c0, int c1,
    const int* __restrict__ cD, int d0, int d1,
    int lane, float& oA, float& oB, float& oC, float& oD)
{
    float aA[4], aB[4], aC[4], aD[4];
    #pragma unroll
    for (int k = 0; k < 4; ++k) { aA[k] = 0.f; aB[k] = 0.f; aC[k] = 0.f; aD[k] = 0.f; }
    int pA = a0, pB = b0, pC = c0, pD = d0;
    while (pA < a1 || pB < b1 || pC < c1 || pD < d1) {
        int iA = 0, iB = 0, iC = 0, iD = 0, mA = 0, mB = 0, mC = 0, mD = 0;
        if (pA < a1) { int e = pA + lane; iA = cA[e < a1 ? e : a1 - 1]; mA = a1 - pA; if (mA > 32) mA = 32; }
        if (pB < b1) { int e = pB + lane; iB = cB[e < b1 ? e : b1 - 1]; mB = b1 - pB; if (mB > 32) mB = 32; }
        if (pC < c1) { int e = pC + lane; iC = cC[e < c1 ? e : c1 - 1]; mC = c1 - pC; if (mC > 32) mC = 32; }
        if (pD < d1) { int e = pD + lane; iD = cD[e < d1 ? e : d1 - 1]; mD = d1 - pD; if (mD > 32) mD = 32; }
        int mm = mA > mB ? mA : mB;
        if (mC > mm) mm = mC;
        if (mD > mm) mm = mD;
        for (int j = 0; j < mm; j += 8) {
            float vA[8], vB[8], vC[8], vD[8];
            bool dA = j < mA, dB = j < mB, dC = j < mC, dD = j < mD;
            if (dA) {
                #pragma unroll
                for (int k = 0; k < 8; ++k)
                    vA[k] = hin[__shfl(iA, (j + k) & 31, 32) * 32 + lane];
            }
            if (dB) {
                #pragma unroll
                for (int k = 0; k < 8; ++k)
                    vB[k] = hin[__shfl(iB, (j + k) & 31, 32) * 32 + lane];
            }
            if (dC) {
                #pragma unroll
                for (int k = 0; k < 8; ++k)
                    vC[k] = hin[__shfl(iC, (j + k) & 31, 32) * 32 + lane];
            }
            if (dD) {
                #pragma unroll
                for (int k = 0; k < 8; ++k)
                    vD[k] = hin[__shfl(iD, (j + k) & 31, 32) * 32 + lane];
            }
            if (dA) {
                #pragma unroll
                for (int k = 0; k < 8; ++k)
                    aA[k & 3] = fmaf(vA[k], (j + k < mA) ? 1.f : 0.f, aA[k & 3]);
            }
            if (dB) {
                #pragma unroll
                for (int k = 0; k < 8; ++k)
                    aB[k & 3] = fmaf(vB[k], (j + k < mB) ? 1.f : 0.f, aB[k & 3]);
            }
            if (dC) {
                #pragma unroll
                for (int k = 0; k < 8; ++k)
                    aC[k & 3] = fmaf(vC[k], (j + k < mC) ? 1.f : 0.f, aC[k & 3]);
            }
            if (dD) {
                #pragma unroll
                for (int k = 0; k < 8; ++k)
                    aD[k & 3] = fmaf(vD[k], (j + k < mD) ? 1.f : 0.f, aD[k & 3]);
            }
        }
        pA += 32; pB += 32; pC += 32; pD += 32;
    }
    int nA = a1 - a0, nB = b1 - b0, nC = c1 - c0, nD = d1 - d0;
    oA = ((aA[0] + aA[1]) + (aA[2] + aA[3])) * (1.0f / (float)(nA > 0 ? nA : 1));
    oB = ((aB[0] + aB[1]) + (aB[2] + aB[3])) * (1.0f / (float)(nB > 0 ? nB : 1));
    oC = ((aC[0] + aC[1]) + (aC[2] + aC[3])) * (1.0f / (float)(nC > 0 ? nC : 1));
    oD = ((aD[0] + aD[1]) + (aD[2] + aD[3])) * (1.0f / (float)(nD > 0 ? nD : 1));
}

__global__ void __launch_bounds__(256) k_sage(
    const float* __restrict__ hin, float* __restrict__ hout,
    const int* __restrict__ csr, const int* __restrict__ off,
    const float* __restrict__ wl, const float* __restrict__ bl, const float* __restrict__ wr,
    int n) {
    __shared__ float wlT[32][33];
    __shared__ float wrT[32][33];
    int tid = threadIdx.x;
    for (int idx = tid; idx < 1024; idx += 256) {
        int j = idx >> 5, k = idx & 31;
        wlT[k][j] = wl[idx];
        wrT[k][j] = wr[idx];
    }
    __syncthreads();
    int lane = tid & 31;
    int g    = blockIdx.x * 8 + (tid >> 5);
    int G    = gridDim.x * 8;
    for (int i = 4 * g; i < n; i += 4 * G) {
        int n0 = i, n1 = i + 1, n2 = i + 2, n3 = i + 3;
        float s0, s1, s2, s3;
        seg_mean_quad(hin, csr, off[n0], off[n0 + 1], csr, off[n1], off[n1 + 1],
                      csr, off[n2], off[n2 + 1], csr, off[n3], off[n3 + 1],
                      lane, s0, s1, s2, s3);
        float h0 = hin[n0 * 32 + lane];
        float h1 = hin[n1 * 32 + lane];
        float h2 = hin[n2 * 32 + lane];
        float h3 = hin[n3 * 32 + lane];
        float bb = bl[lane];
        float A0 = bb, A1 = bb, A2 = bb, A3 = bb;
        #pragma unroll
        for (int k = 0; k < 32; ++k) {
            float wlk = wlT[k][lane], wrk = wrT[k][lane];
            A0 = fmaf(__shfl(s0, k, 32), wlk, A0);
            A0 = fmaf(__shfl(h0, k, 32), wrk, A0);
            A1 = fmaf(__shfl(s1, k, 32), wlk, A1);
            A1 = fmaf(__shfl(h1, k, 32), wrk, A1);
            A2 = fmaf(__shfl(s2, k, 32), wlk, A2);
            A2 = fmaf(__shfl(h2, k, 32), wrk, A2);
            A3 = fmaf(__shfl(s3, k, 32), wlk, A3);
            A3 = fmaf(__shfl(h3, k, 32), wrk, A3);
        }
        hout[n0 * 32 + lane] = fmaxf(A0, 0.f);
        hout[n1 * 32 + lane] = fmaxf(A1, 0.f);
        hout[n2 * 32 + lane] = fmaxf(A2, 0.f);
        hout[n3 * 32 + lane] = fmaxf(A3, 0.f);
    }
}

__global__ void __launch_bounds__(256) k_sage2(
    const float* __restrict__ hin, float* __restrict__ hout,
    const int* __restrict__ csrF, const int* __restrict__ offF,
    const int* __restrict__ csrR, const int* __restrict__ offR,
    const float* __restrict__ wlF, const float* __restrict__ blF, const float* __restrict__ wrF,
    const float* __restrict__ wlR, const float* __restrict__ blR, const float* __restrict__ wrR,
    int n) {
    __shared__ float WLF[32][33], WRF[32][33], WLR[32][33], WRR[32][33];
    int tid = threadIdx.x;
    for (int idx = tid; idx < 1024; idx += 256) {
        int j = idx >> 5, k = idx & 31;
        WLF[k][j] = wlF[idx];
        WRF[k][j] = wrF[idx];
        WLR[k][j] = wlR[idx];
        WRR[k][j] = wrR[idx];
    }
    __syncthreads();
    int lane = tid & 31;
    int g    = blockIdx.x * 8 + (tid >> 5);
    int G    = gridDim.x * 8;
    for (int i = 2 * g; i < n; i += 2 * G) {
        int n0 = i, n1 = i + 1;
        float sF0, sR0, sF1, sR1;
        seg_mean_quad(hin, csrF, offF[n0], offF[n0 + 1], csrR, offR[n0], offR[n0 + 1],
                      csrF, offF[n1], offF[n1 + 1], csrR, offR[n1], offR[n1 + 1],
                      lane, sF0, sR0, sF1, sR1);
        float h0 = hin[n0 * 32 + lane];
        float h1 = hin[n1 * 32 + lane];
        float bF = blF[lane], bR = blR[lane];
        float aF0 = bF, aR0 = bR, aF1 = bF, aR1 = bR;
        #pragma unroll
        for (int k = 0; k < 32; ++k) {
            float f0 = __shfl(sF0, k, 32);
            float r0 = __shfl(sR0, k, 32);
            float f1 = __shfl(sF1, k, 32);
            float r1 = __shfl(sR1, k, 32);
            float hk0 = __shfl(h0, k, 32);
            float hk1 = __shfl(h1, k, 32);
            float wlf = WLF[k][lane], wrf = WRF[k][lane];
            float wlr = WLR[k][lane], wrr = WRR[k][lane];
            aF0 = fmaf(f0, wlf, aF0); aF0 = fmaf(hk0, wrf, aF0);
            aR0 = fmaf(r0, wlr, aR0); aR0 = fmaf(hk0, wrr, aR0);
            aF1 = fmaf(f1, wlf, aF1); aF1 = fmaf(hk1, wrf, aF1);
            aR1 = fmaf(r1, wlr, aR1); aR1 = fmaf(hk1, wrr, aR1);
        }
        hout[n0 * 32 + lane] = fmaxf(aF0, 0.f) + fmaxf(aR0, 0.f);
        hout[n1 * 32 + lane] = fmaxf(aF1, 0.f) + fmaxf(aR1, 0.f);
    }
}

__global__ void k_pair(const float* __restrict__ h, const int* __restrict__ pos1,
                       float* __restrict__ hp, int total) {
    int idx = blockIdx.x * blockDim.x + threadIdx.x;
    int stride = gridDim.x * blockDim.x;
    for (; idx < total; idx += stride) {
        int r = idx >> 5, k = idx & 31;
        int a = pos1[2 * r], b = pos1[2 * r + 1];
        hp[idx] = h[a * 32 + k] * h[b * 32 + k];
    }
}

__global__ void k_final(const float* __restrict__ h, const int* __restrict__ pos2,
                        const float* __restrict__ pw, const float* __restrict__ pb,
                        float* __restrict__ out, int m2) {
    int tid  = threadIdx.x;
    int lane = tid & 31;
    int i    = blockIdx.x * 8 + (tid >> 5);
    if (i >= m2) return;
    int p0 = pos2[2 * i], p1 = pos2[2 * i + 1];
    float v = h[p0 * 32 + lane] * h[p1 * 32 + lane] * pw[lane];
    #pragma unroll
    for (int o = 16; o > 0; o >>= 1) v += __shfl_xor(v, o, 32);
    if (lane == 0) out[i] = v + pb[0];
}

// ---------------- launch ----------------

extern "C" void kernel_launch(void* const* d_in, const int* in_sizes, int n_in,
                              void* d_out, int out_size, void* d_ws, size_t ws_size,
                              hipStream_t stream) {
    const int*   x      = (const int*)d_in[0];
    const int*   edge1  = (const int*)d_in[2];
    const int*   edge2  = (const int*)d_in[3];
    const int*   edge2r = (const int*)d_in[4];
    const int*   pos1   = (const int*)d_in[5];
    const int*   pos2   = (const int*)d_in[6];
    const float* emb    = (const float*)d_in[7];
    const float* gw     = (const float*)d_in[8];
    const float* gb     = (const float*)d_in[9];
    const float* gms    = (const float*)d_in[10];
    const float* c1wl   = (const float*)d_in[11];
    const float* c1bl   = (const float*)d_in[12];
    const float* c1wr   = (const float*)d_in[13];
    const float* c2wl   = (const float*)d_in[14];
    const float* c2bl   = (const float*)d_in[15];
    const float* c2wr   = (const float*)d_in[16];
    const float* c2rwl  = (const float*)d_in[17];
    const float* c2rbl  = (const float*)d_in[18];
    const float* c2rwr  = (const float*)d_in[19];
    const float* pw     = (const float*)d_in[20];
    const float* pb     = (const float*)d_in[21];
    float* out = (float*)d_out;

    char* ws = (char*)d_ws;
    float* hA    = (float*)(ws + OFF_HA);
    float* hB    = (float*)(ws + OFF_HB);
    int*   cnt   = (int*)(ws + OFF_HB);          // overlays hB, dead before k_sage_emb
    int*   csr1  = (int*)(ws + OFF_CSR1);
    int*   csr2  = (int*)(ws + OFF_CSR2);
    int*   csr2r = (int*)(ws + OFF_CSR2R);
    int*   off1  = (int*)(ws + OFF_OFF1);
    int*   off2  = (int*)(ws + OFF_OFF2);
    int*   off2r = (int*)(ws + OFF_OFF2R);
    int*   bsum  = (int*)(ws + OFF_BSUM);
    int*   hist  = (int*)(ws + OFF_HIST);
    float* wlp   = (float*)(ws + OFF_WLP);
    float* wrp   = (float*)(ws + OFF_WRP);
    float* bp    = (float*)(ws + OFF_BP);

    // temp bucketed-edge arrays overlay hA (dead until k_sage layer 2 writes hA)
    int* beF = (int*)(ws + OFF_HA);
    int* beR = (int*)(ws + OFF_HA + 12800000);
    int* be1 = (int*)(ws + OFF_HA);

    hipMemsetAsync(hist, 0, 512, stream);

    // --- GraphNorm stats from x-histogram + layer-1 weight fold ---
    k_histx<<<256, 256, 0, stream>>>(x, hist, NN);
    k_prep<<<1, 256, 0, stream>>>(hist, emb, gw, gb, gms, c1wl, c1bl, c1wr, wlp, wrp, bp);

    // --- CSR build: histogram -> scan -> bin (LDS cursors) -> per-bucket refine ---
    k_hist<<<3 * P_PART, 256, 0, stream>>>(edge2 + E2N, edge2r + E2N, edge1 + E1N, cnt);
    k_scanA<<<SCAN_NB, 256, 0, stream>>>(cnt, bsum);
    k_scanB<<<1, 256, 0, stream>>>(bsum, SCAN_NB);
    k_scanC<<<SCAN_NB, 256, 0, stream>>>(cnt, bsum);
    k_bfillFR<<<2 * P_PART, 256, 0, stream>>>(edge2, edge2 + E2N, edge2r, edge2r + E2N,
                                              cnt, beF, beR);
    k_bcsr2<<<2 * NBKT2, 256, 0, stream>>>(beF, beR, cnt, off2, csr2, off2r, csr2r);
    k_bfill1<<<P_PART, 256, 0, stream>>>(edge1, edge1 + E1N, cnt, be1);
    k_bcsr1<<<NBKT1, 256, 0, stream>>>(be1, cnt, off1, csr1);

    // --- conv1 layer 1: direct from emb via LDS (clobbers cnt region of hB) ---
    k_sage_emb<<<6250, 256, 0, stream>>>(x, emb, hB, csr1, off1, wlp, bp, wrp, NN);

    // --- conv1 layer 2: hB -> hA (clobbers be1/beF temp, now dead) ---
    k_sage<<<2048, 256, 0, stream>>>(hB, hA, csr1, off1,
                                     c1wl + 1024, c1bl + 32, c1wr + 1024, NN);

    // --- pair features: hA (N rows) -> hB (N2 rows; csr1 now dead) ---
    k_pair<<<2048, 256, 0, stream>>>(hA, pos1, hB, N2N * 32);

    // --- conv2: hB -> hA -> hB (fused F+R each layer) ---
    k_sage2<<<2048, 256, 0, stream>>>(hB, hA, csr2, off2, csr2r, off2r,
        c2wl, c2bl, c2wr, c2rwl, c2rbl, c2rwr, N2N);
    k_sage2<<<2048, 256, 0, stream>>>(hA, hB, csr2, off2, csr2r, off2r,
        c2wl + 1024, c2bl + 32, c2wr + 1024, c2rwl + 1024, c2rbl + 32, c2rwr + 1024, N2N);

    // --- head ---
    k_final<<<(MN / 2) / 8, 256, 0, stream>>>(hB, pos2, pw, pb, out, MN / 2);
}